// Round 2
// baseline (769.147 us; speedup 1.0000x reference)
//
#include <hip/hip_runtime.h>
#include <math.h>

#define NN 50000
#define NE 800000

__device__ __forceinline__ float selu_f(float x) {
    const float scale = 1.0507009873554805f;
    const float alpha = 1.6732632423543772f;
    return scale * (x > 0.0f ? x : alpha * expm1f(x));
}

__global__ void k_init_cnt(int* cnt) {
    int i = blockIdx.x * blockDim.x + threadIdx.x;
    if (i < NN) cnt[i] = 0;
}

__global__ void k_hist(const int* __restrict__ dst, int* __restrict__ cnt) {
    int e = blockIdx.x * blockDim.x + threadIdx.x;
    if (e < NE) atomicAdd(&cnt[dst[e]], 1);
}

__global__ void k_dinv(const int* __restrict__ cnt, float* __restrict__ dinv) {
    int i = blockIdx.x * blockDim.x + threadIdx.x;
    if (i < NN) dinv[i] = rsqrtf((float)(cnt[i] + 1));  // +1 self loop; always > 0
}

// single-block exclusive scan over cnt[0..NN) -> rowptr, pos
__global__ void k_scan(const int* __restrict__ cnt, int* __restrict__ rowptr,
                       int* __restrict__ pos) {
    __shared__ int s[1024];
    int tid = threadIdx.x;
    int running = 0;
    const int nch = (NN + 1023) / 1024;
    for (int c = 0; c < nch; c++) {
        int idx = c * 1024 + tid;
        int v = (idx < NN) ? cnt[idx] : 0;
        s[tid] = v;
        __syncthreads();
        for (int off = 1; off < 1024; off <<= 1) {
            int t = (tid >= off) ? s[tid - off] : 0;
            __syncthreads();
            s[tid] += t;
            __syncthreads();
        }
        int incl = s[tid];
        int tot = s[1023];
        int r = running + incl - v;
        if (idx < NN) { rowptr[idx] = r; pos[idx] = r; }
        running += tot;
        __syncthreads();
    }
    if (tid == 0) rowptr[NN] = running;
}

__global__ void k_scatter(const int* __restrict__ src, const int* __restrict__ dst,
                          const float* __restrict__ dinv, int* __restrict__ pos,
                          int* __restrict__ col, float* __restrict__ enorm) {
    int e = blockIdx.x * blockDim.x + threadIdx.x;
    if (e < NE) {
        int s = src[e], d = dst[e];
        int slot = atomicAdd(&pos[d], 1);
        col[slot] = s;
        enorm[slot] = dinv[s] * dinv[d];
    }
}

// out[row][j] = sum_k in[row][k] * W[k][j]   (no bias; bias folded into agg)
template <int K, int J>
__global__ void k_mm(const float* __restrict__ in, const float* __restrict__ W,
                     float* __restrict__ out) {
    constexpr int CG = J / 4;          // col groups of 4
    constexpr int RPB = 256 / CG;      // rows per block
    __shared__ float Ws[K * J];
    for (int i = threadIdx.x; i < K * J; i += 256) Ws[i] = W[i];
    __syncthreads();
    int cg = threadIdx.x % CG;
    int r = threadIdx.x / CG;
    long row = (long)blockIdx.x * RPB + r;
    if (row >= NN) return;
    const float* inr = in + row * K;
    float4 acc = make_float4(0.f, 0.f, 0.f, 0.f);
    #pragma unroll 8
    for (int k = 0; k < K; k++) {
        float a = inr[k];  // broadcast across the CG threads sharing this row
        float4 w = *(const float4*)&Ws[k * J + cg * 4];
        acc.x += a * w.x; acc.y += a * w.y; acc.z += a * w.z; acc.w += a * w.w;
    }
    float* o = out + row * J + cg * 4;
    *(float4*)o = acc;
}

// one wave (64 lanes) per node; lane = feature dim (J=64) or dim & dim+64 (J=128)
template <int J, bool DO_SELU, bool DO_NORM>
__global__ void k_agg(const float* __restrict__ h, const int* __restrict__ rowptr,
                      const int* __restrict__ col, const float* __restrict__ enorm,
                      const float* __restrict__ dinv, const float* __restrict__ bias,
                      float* __restrict__ out) {
    int wave = (blockIdx.x * blockDim.x + threadIdx.x) >> 6;
    int lane = threadIdx.x & 63;
    if (wave >= NN) return;
    const int n = wave;
    float dn = dinv[n];
    float self = dn * dn;
    int beg = rowptr[n], end = rowptr[n + 1];
    if constexpr (J == 128) {
        float a0 = bias[lane]      + self * h[(long)n * 128 + lane];
        float a1 = bias[lane + 64] + self * h[(long)n * 128 + lane + 64];
        for (int e = beg; e < end; e++) {
            int c = col[e];
            float w = enorm[e];
            a0 += w * h[(long)c * 128 + lane];
            a1 += w * h[(long)c * 128 + lane + 64];
        }
        if constexpr (DO_SELU) { a0 = selu_f(a0); a1 = selu_f(a1); }
        out[(long)n * 128 + lane] = a0;
        out[(long)n * 128 + lane + 64] = a1;
    } else {
        float a0 = bias[lane] + self * h[(long)n * 64 + lane];
        for (int e = beg; e < end; e++) {
            int c = col[e];
            float w = enorm[e];
            a0 += w * h[(long)c * 64 + lane];
        }
        if constexpr (DO_SELU) a0 = selu_f(a0);
        if constexpr (DO_NORM) {
            float ss = a0 * a0;
            #pragma unroll
            for (int off = 32; off > 0; off >>= 1) ss += __shfl_xor(ss, off);
            float nrm = sqrtf(ss);
            a0 = a0 / fmaxf(nrm, 1e-12f);
        }
        out[(long)n * 64 + lane] = a0;
    }
}

extern "C" void kernel_launch(void* const* d_in, const int* in_sizes, int n_in,
                              void* d_out, int out_size, void* d_ws, size_t ws_size,
                              hipStream_t stream) {
    const float* x  = (const float*)d_in[0];
    const int* edge = (const int*)d_in[1];
    const float* W1 = (const float*)d_in[2]; const float* b1 = (const float*)d_in[3];
    const float* W2 = (const float*)d_in[4]; const float* b2 = (const float*)d_in[5];
    const float* W3 = (const float*)d_in[6]; const float* b3 = (const float*)d_in[7];
    const float* W4 = (const float*)d_in[8]; const float* b4 = (const float*)d_in[9];
    float* out = (float*)d_out;

    char* ws = (char*)d_ws;
    size_t off = 0;
    auto alloc = [&](size_t bytes) -> void* {
        void* p = ws + off;
        off = (off + bytes + 255) & ~(size_t)255;
        return p;
    };
    int*   cnt    = (int*)alloc((size_t)NN * 4);
    int*   rowptr = (int*)alloc((size_t)(NN + 1) * 4);
    int*   pos    = (int*)alloc((size_t)NN * 4);
    float* dinv   = (float*)alloc((size_t)NN * 4);
    int*   col    = (int*)alloc((size_t)NE * 4);
    float* enorm  = (float*)alloc((size_t)NE * 4);
    float* bufA   = (float*)alloc((size_t)NN * 128 * 4);
    float* bufB   = (float*)alloc((size_t)NN * 128 * 4);

    const int* srcp = edge;
    const int* dstp = edge + NE;

    const int BN = (NN + 255) / 256;
    const int BE = (NE + 255) / 256;

    k_init_cnt<<<BN, 256, 0, stream>>>(cnt);
    k_hist<<<BE, 256, 0, stream>>>(dstp, cnt);
    k_dinv<<<BN, 256, 0, stream>>>(cnt, dinv);
    k_scan<<<1, 1024, 0, stream>>>(cnt, rowptr, pos);
    k_scatter<<<BE, 256, 0, stream>>>(srcp, dstp, dinv, pos, col, enorm);

    const int AGG_B = (NN + 3) / 4;  // 4 waves/block, 1 wave/node

    // layer 1: x(128) -> 128, selu
    k_mm<128, 128><<<(NN + 7) / 8, 256, 0, stream>>>(x, W1, bufA);
    k_agg<128, true, false><<<AGG_B, 256, 0, stream>>>(bufA, rowptr, col, enorm, dinv, b1, bufB);
    // layer 2: 128 -> 128, selu
    k_mm<128, 128><<<(NN + 7) / 8, 256, 0, stream>>>(bufB, W2, bufA);
    k_agg<128, true, false><<<AGG_B, 256, 0, stream>>>(bufA, rowptr, col, enorm, dinv, b2, bufB);
    // layer 3: 128 -> 64, selu
    k_mm<128, 64><<<(NN + 15) / 16, 256, 0, stream>>>(bufB, W3, bufA);
    k_agg<64, true, false><<<AGG_B, 256, 0, stream>>>(bufA, rowptr, col, enorm, dinv, b3, bufB);
    // layer 4: 64 -> 64, no selu, L2-normalize, straight to d_out
    k_mm<64, 64><<<(NN + 15) / 16, 256, 0, stream>>>(bufB, W4, bufA);
    k_agg<64, false, true><<<AGG_B, 256, 0, stream>>>(bufA, rowptr, col, enorm, dinv, b4, out);
}

// Round 3
// 472.331 us; speedup vs baseline: 1.6284x; 1.6284x over previous
//
#include <hip/hip_runtime.h>
#include <math.h>

#define NN 50000
#define NE 800000

__device__ __forceinline__ float selu_f(float x) {
    const float scale = 1.0507009873554805f;
    const float alpha = 1.6732632423543772f;
    return scale * (x > 0.0f ? x : alpha * expm1f(x));
}

__global__ void k_init_cnt(int* cnt) {
    int i = blockIdx.x * blockDim.x + threadIdx.x;
    if (i < NN) cnt[i] = 0;
}

__global__ void k_hist(const int* __restrict__ dst, int* __restrict__ cnt) {
    int e = blockIdx.x * blockDim.x + threadIdx.x;
    if (e < NE) atomicAdd(&cnt[dst[e]], 1);
}

__global__ void k_dinv(const int* __restrict__ cnt, float* __restrict__ dinv) {
    int i = blockIdx.x * blockDim.x + threadIdx.x;
    if (i < NN) dinv[i] = rsqrtf((float)(cnt[i] + 1));  // +1 self loop; always > 0
}

// ---- two-level exclusive scan over cnt[0..NN) -> rowptr, pos -----------
// A: per-1024 chunk local exclusive scan (values written to rowptr), chunk
//    totals to partials.  B: 1-wave scan of chunk totals.  C: add offsets.
#define NB1 ((NN + 1023) / 1024)

__global__ void k_scanA(const int* __restrict__ cnt, int* __restrict__ rowptr,
                        int* __restrict__ partials) {
    __shared__ int wsum[4];
    int tid = threadIdx.x;
    int lane = tid & 63, wave = tid >> 6;
    int base = blockIdx.x * 1024 + tid * 4;
    int e0 = 0, e1 = 0, e2 = 0, e3 = 0;
    if (base + 3 < NN) {
        int4 v = *(const int4*)&cnt[base];
        e0 = v.x; e1 = v.y; e2 = v.z; e3 = v.w;
    } else {
        if (base + 0 < NN) e0 = cnt[base + 0];
        if (base + 1 < NN) e1 = cnt[base + 1];
        if (base + 2 < NN) e2 = cnt[base + 2];
        if (base + 3 < NN) e3 = cnt[base + 3];
    }
    int lsum = e0 + e1 + e2 + e3;
    int s = lsum;
    #pragma unroll
    for (int off = 1; off < 64; off <<= 1) {
        int t = __shfl_up(s, off, 64);
        if (lane >= off) s += t;
    }
    if (lane == 63) wsum[wave] = s;
    __syncthreads();
    int wbase = 0;
    #pragma unroll
    for (int w = 0; w < 4; w++) wbase += (w < wave) ? wsum[w] : 0;
    int excl = wbase + s - lsum;
    if (base + 0 < NN) rowptr[base + 0] = excl;
    if (base + 1 < NN) rowptr[base + 1] = excl + e0;
    if (base + 2 < NN) rowptr[base + 2] = excl + e0 + e1;
    if (base + 3 < NN) rowptr[base + 3] = excl + e0 + e1 + e2;
    if (tid == 0) {
        // wsum written; recompute total after sync via all 4
        int tot = wsum[0] + wsum[1] + wsum[2] + wsum[3];
        partials[blockIdx.x] = tot;
    }
}

__global__ void k_scanB(int* __restrict__ partials, int* __restrict__ partials2,
                        int* __restrict__ rowptr) {
    int lane = threadIdx.x;
    int v = (lane < NB1) ? partials[lane] : 0;
    int s = v;
    #pragma unroll
    for (int off = 1; off < 64; off <<= 1) {
        int t = __shfl_up(s, off, 64);
        if (lane >= off) s += t;
    }
    if (lane < NB1) partials2[lane] = s - v;  // exclusive
    if (lane == 63) rowptr[NN] = s;           // grand total
}

__global__ void k_scanC(int* __restrict__ rowptr, int* __restrict__ pos,
                        const int* __restrict__ partials2) {
    int off = partials2[blockIdx.x];
    int base = blockIdx.x * 1024 + threadIdx.x * 4;
    #pragma unroll
    for (int j = 0; j < 4; j++) {
        int idx = base + j;
        if (idx < NN) {
            int r = rowptr[idx] + off;
            rowptr[idx] = r;
            pos[idx] = r;
        }
    }
}

__global__ void k_scatter(const int* __restrict__ src, const int* __restrict__ dst,
                          const float* __restrict__ dinv, int* __restrict__ pos,
                          int* __restrict__ col, float* __restrict__ enorm) {
    int e = blockIdx.x * blockDim.x + threadIdx.x;
    if (e < NE) {
        int s = src[e], d = dst[e];
        int slot = atomicAdd(&pos[d], 1);
        col[slot] = s;
        enorm[slot] = dinv[s] * dinv[d];
    }
}

// ---- register-tiled matmul: out[row][j] = sum_k in[row][k]*W[k][j] ------
// W fully staged in LDS; 32/64-row tiles staged in LDS; each thread owns
// RPT=4 rows x 4 cols (16 independent FMA chains per k-step).
template <int K, int J>
__global__ void __launch_bounds__(256) k_mm2(const float* __restrict__ in,
                                             const float* __restrict__ W,
                                             float* __restrict__ out) {
    constexpr int CG = J / 4;              // col groups (float4 wide)
    constexpr int RG = 256 / CG;           // row groups
    constexpr int RPT = 4;                 // rows per thread
    constexpr int ROWS = RG * RPT;         // rows per tile
    constexpr int RSTRIDE = (J == 128) ? K : (K + 4);  // pad to dodge bank conflicts when >2 rgs/wave
    constexpr int NT = (NN + ROWS - 1) / ROWS;

    __shared__ float Ws[K * J];
    __shared__ float Rs[ROWS * RSTRIDE];

    for (int i = threadIdx.x; i < K * J / 4; i += 256)
        *(float4*)&Ws[i * 4] = *(const float4*)&W[i * 4];

    const int cg = threadIdx.x % CG;
    const int rg = threadIdx.x / CG;

    for (int tile = blockIdx.x; tile < NT; tile += gridDim.x) {
        const int row0 = tile * ROWS;
        __syncthreads();
        // stage ROWS x K floats (float4 granularity)
        constexpr int NF4 = ROWS * K / 4;
        for (int f = threadIdx.x; f < NF4; f += 256) {
            int r = f / (K / 4);
            int seg = f % (K / 4);
            int rg_ = row0 + r;
            if (rg_ < NN)
                *(float4*)&Rs[r * RSTRIDE + seg * 4] = *(const float4*)&in[(size_t)rg_ * K + seg * 4];
        }
        __syncthreads();

        float4 acc[RPT];
        #pragma unroll
        for (int r = 0; r < RPT; r++) acc[r] = make_float4(0.f, 0.f, 0.f, 0.f);

        #pragma unroll 8
        for (int k = 0; k < K; k++) {
            float4 w = *(const float4*)&Ws[k * J + cg * 4];
            #pragma unroll
            for (int r = 0; r < RPT; r++) {
                float a = Rs[(rg * RPT + r) * RSTRIDE + k];
                acc[r].x += a * w.x; acc[r].y += a * w.y;
                acc[r].z += a * w.z; acc[r].w += a * w.w;
            }
        }

        #pragma unroll
        for (int r = 0; r < RPT; r++) {
            int row = row0 + rg * RPT + r;
            if (row < NN)
                *(float4*)&out[(size_t)row * J + cg * 4] = acc[r];
        }
    }
}

// ---- CSR gather-aggregate: one wave per node --------------------------
template <int J, bool DO_SELU, bool DO_NORM>
__global__ void k_agg(const float* __restrict__ h, const int* __restrict__ rowptr,
                      const int* __restrict__ col, const float* __restrict__ enorm,
                      const float* __restrict__ dinv, const float* __restrict__ bias,
                      float* __restrict__ out) {
    int wave = (blockIdx.x * blockDim.x + threadIdx.x) >> 6;
    int lane = threadIdx.x & 63;
    if (wave >= NN) return;
    const int n = wave;
    float dn = dinv[n];
    float self = dn * dn;
    int beg = rowptr[n], end = rowptr[n + 1];
    if constexpr (J == 128) {
        const float2* h2 = (const float2*)h;
        float2 bv = ((const float2*)bias)[lane];
        float2 hv = h2[(size_t)n * 64 + lane];
        float ax = bv.x + self * hv.x;
        float ay = bv.y + self * hv.y;
        int e = beg;
        for (; e + 3 < end; e += 4) {
            int c0 = col[e], c1 = col[e + 1], c2 = col[e + 2], c3 = col[e + 3];
            float w0 = enorm[e], w1 = enorm[e + 1], w2 = enorm[e + 2], w3 = enorm[e + 3];
            float2 v0 = h2[(size_t)c0 * 64 + lane];
            float2 v1 = h2[(size_t)c1 * 64 + lane];
            float2 v2 = h2[(size_t)c2 * 64 + lane];
            float2 v3 = h2[(size_t)c3 * 64 + lane];
            ax += w0 * v0.x; ay += w0 * v0.y;
            ax += w1 * v1.x; ay += w1 * v1.y;
            ax += w2 * v2.x; ay += w2 * v2.y;
            ax += w3 * v3.x; ay += w3 * v3.y;
        }
        for (; e < end; e++) {
            int c = col[e];
            float w = enorm[e];
            float2 v = h2[(size_t)c * 64 + lane];
            ax += w * v.x; ay += w * v.y;
        }
        if constexpr (DO_SELU) { ax = selu_f(ax); ay = selu_f(ay); }
        ((float2*)out)[(size_t)n * 64 + lane] = make_float2(ax, ay);
    } else {
        float a0 = bias[lane] + self * h[(size_t)n * 64 + lane];
        int e = beg;
        for (; e + 3 < end; e += 4) {
            int c0 = col[e], c1 = col[e + 1], c2 = col[e + 2], c3 = col[e + 3];
            float w0 = enorm[e], w1 = enorm[e + 1], w2 = enorm[e + 2], w3 = enorm[e + 3];
            float v0 = h[(size_t)c0 * 64 + lane];
            float v1 = h[(size_t)c1 * 64 + lane];
            float v2 = h[(size_t)c2 * 64 + lane];
            float v3 = h[(size_t)c3 * 64 + lane];
            a0 += w0 * v0; a0 += w1 * v1; a0 += w2 * v2; a0 += w3 * v3;
        }
        for (; e < end; e++) {
            a0 += enorm[e] * h[(size_t)col[e] * 64 + lane];
        }
        if constexpr (DO_SELU) a0 = selu_f(a0);
        if constexpr (DO_NORM) {
            float ss = a0 * a0;
            #pragma unroll
            for (int off = 32; off > 0; off >>= 1) ss += __shfl_xor(ss, off);
            float nrm = sqrtf(ss);
            a0 = a0 / fmaxf(nrm, 1e-12f);
        }
        out[(size_t)n * 64 + lane] = a0;
    }
}

extern "C" void kernel_launch(void* const* d_in, const int* in_sizes, int n_in,
                              void* d_out, int out_size, void* d_ws, size_t ws_size,
                              hipStream_t stream) {
    const float* x  = (const float*)d_in[0];
    const int* edge = (const int*)d_in[1];
    const float* W1 = (const float*)d_in[2]; const float* b1 = (const float*)d_in[3];
    const float* W2 = (const float*)d_in[4]; const float* b2 = (const float*)d_in[5];
    const float* W3 = (const float*)d_in[6]; const float* b3 = (const float*)d_in[7];
    const float* W4 = (const float*)d_in[8]; const float* b4 = (const float*)d_in[9];
    float* out = (float*)d_out;

    char* ws = (char*)d_ws;
    size_t off = 0;
    auto alloc = [&](size_t bytes) -> void* {
        void* p = ws + off;
        off = (off + bytes + 255) & ~(size_t)255;
        return p;
    };
    int*   cnt    = (int*)alloc((size_t)NN * 4);
    int*   rowptr = (int*)alloc((size_t)(NN + 1) * 4);
    int*   pos    = (int*)alloc((size_t)NN * 4);
    float* dinv   = (float*)alloc((size_t)NN * 4);
    int*   col    = (int*)alloc((size_t)NE * 4);
    float* enorm  = (float*)alloc((size_t)NE * 4);
    float* bufA   = (float*)alloc((size_t)NN * 128 * 4);
    float* bufB   = (float*)alloc((size_t)NN * 128 * 4);
    int*   part1  = (int*)alloc(64 * 4);
    int*   part2  = (int*)alloc(64 * 4);

    const int* srcp = edge;
    const int* dstp = edge + NE;

    const int BN = (NN + 255) / 256;
    const int BE = (NE + 255) / 256;

    k_init_cnt<<<BN, 256, 0, stream>>>(cnt);
    k_hist<<<BE, 256, 0, stream>>>(dstp, cnt);
    k_dinv<<<BN, 256, 0, stream>>>(cnt, dinv);
    k_scanA<<<NB1, 256, 0, stream>>>(cnt, rowptr, part1);
    k_scanB<<<1, 64, 0, stream>>>(part1, part2, rowptr);
    k_scanC<<<NB1, 256, 0, stream>>>(rowptr, pos, part2);
    k_scatter<<<BE, 256, 0, stream>>>(srcp, dstp, dinv, pos, col, enorm);

    const int AGG_B = (NN + 3) / 4;  // 4 waves/block, 1 wave/node
    const int MMG = 512;

    // layer 1: x(128) -> 128, selu
    k_mm2<128, 128><<<MMG, 256, 0, stream>>>(x, W1, bufA);
    k_agg<128, true, false><<<AGG_B, 256, 0, stream>>>(bufA, rowptr, col, enorm, dinv, b1, bufB);
    // layer 2: 128 -> 128, selu
    k_mm2<128, 128><<<MMG, 256, 0, stream>>>(bufB, W2, bufA);
    k_agg<128, true, false><<<AGG_B, 256, 0, stream>>>(bufA, rowptr, col, enorm, dinv, b2, bufB);
    // layer 3: 128 -> 64, selu
    k_mm2<128, 64><<<MMG, 256, 0, stream>>>(bufB, W3, bufA);
    k_agg<64, true, false><<<AGG_B, 256, 0, stream>>>(bufA, rowptr, col, enorm, dinv, b3, bufB);
    // layer 4: 64 -> 64, no selu, L2-normalize, straight to d_out
    k_mm2<64, 64><<<MMG, 256, 0, stream>>>(bufB, W4, bufA);
    k_agg<64, false, true><<<AGG_B, 256, 0, stream>>>(bufA, rowptr, col, enorm, dinv, b4, out);
}

// Round 8
// 429.772 us; speedup vs baseline: 1.7897x; 1.0990x over previous
//
#include <hip/hip_runtime.h>
#include <math.h>

#define NN 50000
#define NE 800000

__device__ __forceinline__ float selu_f(float x) {
    const float scale = 1.0507009873554805f;
    const float alpha = 1.6732632423543772f;
    return scale * (x > 0.0f ? x : alpha * expm1f(x));
}

// bf16 pack/unpack (RNE). low 16 bits = even dim, high 16 = odd dim.
__device__ __forceinline__ unsigned rnd_bf16(float f) {
    unsigned u = __float_as_uint(f);
    return (u + 0x7fffu + ((u >> 16) & 1u)) >> 16;
}
__device__ __forceinline__ unsigned pack_pair(float a, float b) {
    return (rnd_bf16(b) << 16) | rnd_bf16(a);
}
__device__ __forceinline__ float lo_f(unsigned u) { return __uint_as_float(u << 16); }
__device__ __forceinline__ float hi_f(unsigned u) { return __uint_as_float(u & 0xffff0000u); }

__global__ void k_init_cnt(int* cnt) {
    int i = blockIdx.x * blockDim.x + threadIdx.x;
    if (i < NN) cnt[i] = 0;
}

__global__ void k_hist(const int* __restrict__ dst, int* __restrict__ cnt) {
    int e = blockIdx.x * blockDim.x + threadIdx.x;
    if (e < NE) atomicAdd(&cnt[dst[e]], 1);
}

__global__ void k_dinv(const int* __restrict__ cnt, float* __restrict__ dinv) {
    int i = blockIdx.x * blockDim.x + threadIdx.x;
    if (i < NN) dinv[i] = rsqrtf((float)(cnt[i] + 1));  // +1 self loop; always > 0
}

// ---- two-level exclusive scan over cnt[0..NN) -> rowptr, pos -----------
#define NB1 ((NN + 1023) / 1024)

__global__ void k_scanA(const int* __restrict__ cnt, int* __restrict__ rowptr,
                        int* __restrict__ partials) {
    __shared__ int wsum[4];
    int tid = threadIdx.x;
    int lane = tid & 63, wave = tid >> 6;
    int base = blockIdx.x * 1024 + tid * 4;
    int e0 = 0, e1 = 0, e2 = 0, e3 = 0;
    if (base + 3 < NN) {
        int4 v = *(const int4*)&cnt[base];
        e0 = v.x; e1 = v.y; e2 = v.z; e3 = v.w;
    } else {
        if (base + 0 < NN) e0 = cnt[base + 0];
        if (base + 1 < NN) e1 = cnt[base + 1];
        if (base + 2 < NN) e2 = cnt[base + 2];
        if (base + 3 < NN) e3 = cnt[base + 3];
    }
    int lsum = e0 + e1 + e2 + e3;
    int s = lsum;
    #pragma unroll
    for (int off = 1; off < 64; off <<= 1) {
        int t = __shfl_up(s, off, 64);
        if (lane >= off) s += t;
    }
    if (lane == 63) wsum[wave] = s;
    __syncthreads();
    int wbase = 0;
    #pragma unroll
    for (int w = 0; w < 4; w++) wbase += (w < wave) ? wsum[w] : 0;
    int excl = wbase + s - lsum;
    if (base + 0 < NN) rowptr[base + 0] = excl;
    if (base + 1 < NN) rowptr[base + 1] = excl + e0;
    if (base + 2 < NN) rowptr[base + 2] = excl + e0 + e1;
    if (base + 3 < NN) rowptr[base + 3] = excl + e0 + e1 + e2;
    if (tid == 0)
        partials[blockIdx.x] = wsum[0] + wsum[1] + wsum[2] + wsum[3];
}

__global__ void k_scanB(int* __restrict__ partials, int* __restrict__ partials2,
                        int* __restrict__ rowptr) {
    int lane = threadIdx.x;
    int v = (lane < NB1) ? partials[lane] : 0;
    int s = v;
    #pragma unroll
    for (int off = 1; off < 64; off <<= 1) {
        int t = __shfl_up(s, off, 64);
        if (lane >= off) s += t;
    }
    if (lane < NB1) partials2[lane] = s - v;  // exclusive
    if (lane == 63) rowptr[NN] = s;           // grand total
}

__global__ void k_scanC(int* __restrict__ rowptr, int* __restrict__ pos,
                        const int* __restrict__ partials2) {
    int off = partials2[blockIdx.x];
    int base = blockIdx.x * 1024 + threadIdx.x * 4;
    #pragma unroll
    for (int j = 0; j < 4; j++) {
        int idx = base + j;
        if (idx < NN) {
            int r = rowptr[idx] + off;
            rowptr[idx] = r;
            pos[idx] = r;
        }
    }
}

// edat[slot] = (src, bitcast(norm)) — one 8 B record per edge
__global__ void k_scatter(const int* __restrict__ src, const int* __restrict__ dst,
                          const float* __restrict__ dinv, int* __restrict__ pos,
                          int2* __restrict__ edat) {
    int e = blockIdx.x * blockDim.x + threadIdx.x;
    if (e < NE) {
        int s = src[e], d = dst[e];
        int slot = atomicAdd(&pos[d], 1);
        edat[slot] = make_int2(s, __float_as_int(dinv[s] * dinv[d]));
    }
}

// ---- register-tiled matmul -> packed-bf16 table ------------------------
// out table: row-major, J/2 uints per row (pair-packed dims).
template <int K, int J>
__global__ void __launch_bounds__(256) k_mm2(const float* __restrict__ in,
                                             const float* __restrict__ W,
                                             unsigned* __restrict__ out) {
    constexpr int CG = J / 4;              // col groups (float4 wide)
    constexpr int RG = 256 / CG;           // row groups
    constexpr int RPT = 4;                 // rows per thread
    constexpr int ROWS = RG * RPT;         // rows per tile
    constexpr int RSTRIDE = (J == 128) ? K : (K + 4);
    constexpr int NT = (NN + ROWS - 1) / ROWS;

    __shared__ float Ws[K * J];
    __shared__ float Rs[ROWS * RSTRIDE];

    for (int i = threadIdx.x; i < K * J / 4; i += 256)
        *(float4*)&Ws[i * 4] = *(const float4*)&W[i * 4];

    const int cg = threadIdx.x % CG;
    const int rg = threadIdx.x / CG;

    for (int tile = blockIdx.x; tile < NT; tile += gridDim.x) {
        const int row0 = tile * ROWS;
        __syncthreads();
        constexpr int NF4 = ROWS * K / 4;
        for (int f = threadIdx.x; f < NF4; f += 256) {
            int r = f / (K / 4);
            int seg = f % (K / 4);
            int rr = row0 + r;
            if (rr < NN)
                *(float4*)&Rs[r * RSTRIDE + seg * 4] = *(const float4*)&in[(size_t)rr * K + seg * 4];
        }
        __syncthreads();

        float4 acc[RPT];
        #pragma unroll
        for (int r = 0; r < RPT; r++) acc[r] = make_float4(0.f, 0.f, 0.f, 0.f);

        #pragma unroll 8
        for (int k = 0; k < K; k++) {
            float4 w = *(const float4*)&Ws[k * J + cg * 4];
            #pragma unroll
            for (int r = 0; r < RPT; r++) {
                float a = Rs[(rg * RPT + r) * RSTRIDE + k];
                acc[r].x += a * w.x; acc[r].y += a * w.y;
                acc[r].z += a * w.z; acc[r].w += a * w.w;
            }
        }

        #pragma unroll
        for (int r = 0; r < RPT; r++) {
            int row = row0 + rg * RPT + r;
            if (row < NN) {
                uint2 p;
                p.x = pack_pair(acc[r].x, acc[r].y);
                p.y = pack_pair(acc[r].z, acc[r].w);
                *(uint2*)&out[(size_t)row * (J / 2) + cg * 2] = p;
            }
        }
    }
}

// ---- 128-dim agg: one wave per node; lane owns dims (2L, 2L+1) ---------
template <bool DO_SELU>
__global__ void k_agg128(const unsigned* __restrict__ tab, const int* __restrict__ rowptr,
                         const int2* __restrict__ edat, const float* __restrict__ dinv,
                         const float* __restrict__ bias, float* __restrict__ out) {
    int n = (blockIdx.x * blockDim.x + threadIdx.x) >> 6;
    int lane = threadIdx.x & 63;
    if (n >= NN) return;
    float dn = dinv[n];
    float self = dn * dn;
    int beg = rowptr[n], end = rowptr[n + 1];

    float2 bv = ((const float2*)bias)[lane];
    unsigned su = tab[(size_t)n * 64 + lane];
    float ax = bv.x + self * lo_f(su);
    float ay = bv.y + self * hi_f(su);

    int e = beg;
    for (; e + 7 < end; e += 8) {
        int2 m0 = edat[e + 0], m1 = edat[e + 1], m2 = edat[e + 2], m3 = edat[e + 3];
        int2 m4 = edat[e + 4], m5 = edat[e + 5], m6 = edat[e + 6], m7 = edat[e + 7];
        unsigned g0 = tab[(size_t)m0.x * 64 + lane];
        unsigned g1 = tab[(size_t)m1.x * 64 + lane];
        unsigned g2 = tab[(size_t)m2.x * 64 + lane];
        unsigned g3 = tab[(size_t)m3.x * 64 + lane];
        unsigned g4 = tab[(size_t)m4.x * 64 + lane];
        unsigned g5 = tab[(size_t)m5.x * 64 + lane];
        unsigned g6 = tab[(size_t)m6.x * 64 + lane];
        unsigned g7 = tab[(size_t)m7.x * 64 + lane];
        float w0 = __int_as_float(m0.y), w1 = __int_as_float(m1.y);
        float w2 = __int_as_float(m2.y), w3 = __int_as_float(m3.y);
        float w4 = __int_as_float(m4.y), w5 = __int_as_float(m5.y);
        float w6 = __int_as_float(m6.y), w7 = __int_as_float(m7.y);
        ax += w0 * lo_f(g0); ay += w0 * hi_f(g0);
        ax += w1 * lo_f(g1); ay += w1 * hi_f(g1);
        ax += w2 * lo_f(g2); ay += w2 * hi_f(g2);
        ax += w3 * lo_f(g3); ay += w3 * hi_f(g3);
        ax += w4 * lo_f(g4); ay += w4 * hi_f(g4);
        ax += w5 * lo_f(g5); ay += w5 * hi_f(g5);
        ax += w6 * lo_f(g6); ay += w6 * hi_f(g6);
        ax += w7 * lo_f(g7); ay += w7 * hi_f(g7);
    }
    for (; e < end; e++) {
        int2 m = edat[e];
        float w = __int_as_float(m.y);
        unsigned g = tab[(size_t)m.x * 64 + lane];
        ax += w * lo_f(g); ay += w * hi_f(g);
    }
    if constexpr (DO_SELU) { ax = selu_f(ax); ay = selu_f(ay); }
    ((float2*)out)[(size_t)n * 64 + lane] = make_float2(ax, ay);
}

// ---- 64-dim agg: one wave per node, 2 edges in flight (32 lanes each) --
template <bool DO_SELU, bool DO_NORM>
__global__ void k_agg64(const unsigned* __restrict__ tab, const int* __restrict__ rowptr,
                        const int2* __restrict__ edat, const float* __restrict__ dinv,
                        const float* __restrict__ bias, float* __restrict__ out) {
    int n = (blockIdx.x * blockDim.x + threadIdx.x) >> 6;
    int lane = threadIdx.x & 63;
    if (n >= NN) return;
    int half = lane >> 5;
    int sub = lane & 31;
    float dn = dinv[n];
    float self = dn * dn;
    int beg = rowptr[n], end = rowptr[n + 1];

    float a0 = 0.f, a1 = 0.f;
    int e = beg + half;
    for (; e + 6 < end; e += 8) {  // 4 edges for this half
        int2 m0 = edat[e + 0], m1 = edat[e + 2], m2 = edat[e + 4], m3 = edat[e + 6];
        unsigned g0 = tab[(size_t)m0.x * 32 + sub];
        unsigned g1 = tab[(size_t)m1.x * 32 + sub];
        unsigned g2 = tab[(size_t)m2.x * 32 + sub];
        unsigned g3 = tab[(size_t)m3.x * 32 + sub];
        float w0 = __int_as_float(m0.y), w1 = __int_as_float(m1.y);
        float w2 = __int_as_float(m2.y), w3 = __int_as_float(m3.y);
        a0 += w0 * lo_f(g0); a1 += w0 * hi_f(g0);
        a0 += w1 * lo_f(g1); a1 += w1 * hi_f(g1);
        a0 += w2 * lo_f(g2); a1 += w2 * hi_f(g2);
        a0 += w3 * lo_f(g3); a1 += w3 * hi_f(g3);
    }
    for (; e < end; e += 2) {
        int2 m = edat[e];
        float w = __int_as_float(m.y);
        unsigned g = tab[(size_t)m.x * 32 + sub];
        a0 += w * lo_f(g); a1 += w * hi_f(g);
    }
    // combine the two halves
    a0 += __shfl_xor(a0, 32);
    a1 += __shfl_xor(a1, 32);
    // self + bias once
    float2 bv = ((const float2*)bias)[sub];
    unsigned su = tab[(size_t)n * 32 + sub];
    a0 += bv.x + self * lo_f(su);
    a1 += bv.y + self * hi_f(su);
    if constexpr (DO_SELU) { a0 = selu_f(a0); a1 = selu_f(a1); }
    if constexpr (DO_NORM) {
        float ss = a0 * a0 + a1 * a1;
        #pragma unroll
        for (int off = 16; off > 0; off >>= 1) ss += __shfl_xor(ss, off);
        float nrm = sqrtf(ss);
        float inv = 1.0f / fmaxf(nrm, 1e-12f);
        a0 *= inv; a1 *= inv;
    }
    if (half == 0)
        ((float2*)out)[(size_t)n * 32 + sub] = make_float2(a0, a1);
}

extern "C" void kernel_launch(void* const* d_in, const int* in_sizes, int n_in,
                              void* d_out, int out_size, void* d_ws, size_t ws_size,
                              hipStream_t stream) {
    const float* x  = (const float*)d_in[0];
    const int* edge = (const int*)d_in[1];
    const float* W1 = (const float*)d_in[2]; const float* b1 = (const float*)d_in[3];
    const float* W2 = (const float*)d_in[4]; const float* b2 = (const float*)d_in[5];
    const float* W3 = (const float*)d_in[6]; const float* b3 = (const float*)d_in[7];
    const float* W4 = (const float*)d_in[8]; const float* b4 = (const float*)d_in[9];
    float* out = (float*)d_out;

    char* ws = (char*)d_ws;
    size_t off = 0;
    auto alloc = [&](size_t bytes) -> void* {
        void* p = ws + off;
        off = (off + bytes + 255) & ~(size_t)255;
        return p;
    };
    int*      cnt    = (int*)alloc((size_t)NN * 4);
    int*      rowptr = (int*)alloc((size_t)(NN + 1) * 4);
    int*      pos    = (int*)alloc((size_t)NN * 4);
    float*    dinv   = (float*)alloc((size_t)NN * 4);
    int2*     edat   = (int2*)alloc((size_t)NE * 8);
    unsigned* tab    = (unsigned*)alloc((size_t)NN * 64 * 4);  // packed bf16 pairs
    float*    bufA   = (float*)alloc((size_t)NN * 128 * 4);
    float*    bufB   = (float*)alloc((size_t)NN * 128 * 4);
    int*      part1  = (int*)alloc(64 * 4);
    int*      part2  = (int*)alloc(64 * 4);

    const int* srcp = edge;
    const int* dstp = edge + NE;

    const int BN = (NN + 255) / 256;
    const int BE = (NE + 255) / 256;

    k_init_cnt<<<BN, 256, 0, stream>>>(cnt);
    k_hist<<<BE, 256, 0, stream>>>(dstp, cnt);
    k_dinv<<<BN, 256, 0, stream>>>(cnt, dinv);
    k_scanA<<<NB1, 256, 0, stream>>>(cnt, rowptr, part1);
    k_scanB<<<1, 64, 0, stream>>>(part1, part2, rowptr);
    k_scanC<<<NB1, 256, 0, stream>>>(rowptr, pos, part2);
    k_scatter<<<BE, 256, 0, stream>>>(srcp, dstp, dinv, pos, edat);

    const int AGG_B = (NN + 3) / 4;  // 4 waves/block, 1 wave/node
    const int MMG = 512;

    // layer 1: x(128) -> 128, selu
    k_mm2<128, 128><<<MMG, 256, 0, stream>>>(x, W1, tab);
    k_agg128<true><<<AGG_B, 256, 0, stream>>>(tab, rowptr, edat, dinv, b1, bufA);
    // layer 2: 128 -> 128, selu
    k_mm2<128, 128><<<MMG, 256, 0, stream>>>(bufA, W2, tab);
    k_agg128<true><<<AGG_B, 256, 0, stream>>>(tab, rowptr, edat, dinv, b2, bufB);
    // layer 3: 128 -> 64, selu
    k_mm2<128, 64><<<MMG, 256, 0, stream>>>(bufB, W3, tab);
    k_agg64<true, false><<<AGG_B, 256, 0, stream>>>(tab, rowptr, edat, dinv, b3, bufA);
    // layer 4: 64 -> 64, no selu, L2-normalize, straight to d_out
    k_mm2<64, 64><<<MMG, 256, 0, stream>>>(bufA, W4, tab);
    k_agg64<false, true><<<AGG_B, 256, 0, stream>>>(tab, rowptr, edat, dinv, b4, out);
}